// Round 8
// baseline (284.634 us; speedup 1.0000x reference)
//
#include <hip/hip_runtime.h>
#include <hip/hip_bf16.h>

#define NROWS 16384
#define DDIM  256
#define LOG2E 1.44269504088896f

typedef __attribute__((ext_vector_type(8))) short bh8;    // 8 x bf16 (4 VGPR)
typedef __attribute__((ext_vector_type(4))) short bh4;
typedef __attribute__((ext_vector_type(4))) float fx4;
typedef __attribute__((ext_vector_type(16))) float fx16;  // 32x32 accumulator

__device__ __forceinline__ short f2bf(float x) {
  __hip_bfloat16 h = __float2bfloat16(x);
  return *reinterpret_cast<short*>(&h);
}

__device__ __forceinline__ float fexp2(float x) {
#if __has_builtin(__builtin_amdgcn_exp2f)
  return __builtin_amdgcn_exp2f(x);   // v_exp_f32: D = 2^S0
#else
  return __expf(x * 0.6931471805599453f);
#endif
}

__device__ __forceinline__ fx16 fzero16() {
  fx16 z;
#pragma unroll
  for (int q = 0; q < 16; ++q) z[q] = 0.f;
  return z;
}

// exact softplus, used only on the 16384 diagonal elements
__device__ __forceinline__ float softplus_f(float y) {
  float a = fabsf(y);
  float t = __expf(-a);
  float l;
  if (t < 0.125f) {
    l = t * (1.0f - t * (0.5f - 0.333333333f * t));
  } else {
    l = log1pf(t);
  }
  return fmaxf(y, 0.0f) + l;
}

__global__ void cast_bf16_kernel(const float* __restrict__ in,
                                 unsigned short* __restrict__ out) {
  int i = (blockIdx.x * blockDim.x + threadIdx.x) * 8;
  float4 v0 = *(const float4*)(in + i);
  float4 v1 = *(const float4*)(in + i + 4);
  bh8 o;
  o[0] = f2bf(v0.x); o[1] = f2bf(v0.y); o[2] = f2bf(v0.z); o[3] = f2bf(v0.w);
  o[4] = f2bf(v1.x); o[5] = f2bf(v1.y); o[6] = f2bf(v1.z); o[7] = f2bf(v1.w);
  *(bh8*)((unsigned short*)out + i) = o;
}

// ================= persistent strip kernel: A-in-registers ================
// 256 blocks (1/CU), 512 threads = 8 waves (2 wr x 4 wc), wave tile 64x64 of
// mfma_f32_32x32x16_bf16 (2x2 fx16). Block owns 128 img rows x 8192 txt cols.
// A slice (64 rows x 256 k per wave) lives in 128 VGPRs for the whole kernel
// (areg[2][16], static indices only). LDS = B ring of 4 x 32KB; chunk =
// 256 cols x 64 k; ring period 4 == kc -> compile-time buffer binding.
// Chunk = [vmcnt(8) | barrier | 8 ds_read | lgkm0 | stage(t+3) | 16 MFMA].
// NOTE (R7 lesson): __launch_bounds__ second arg MUST be 1 — at 2 it caps
// VGPR at 128 and the whole A/acc working set (~200 VGPR) spills to scratch
// (FETCH_SIZE 25->175MB, WRITE_SIZE 44MB, dur 283us). Grid is 1 block/CU by
// construction, so there is nothing to gain from a 2-block bound anyway.

// stage chunk (bt2,kc2) into buffer bufp (4 x global_load_lds / thread)
#define STAGE(bt2, kc2, bufp)                                                  \
  do {                                                                         \
    _Pragma("unroll")                                                          \
    for (int it_ = 0; it_ < 4; ++it_) {                                        \
      __builtin_amdgcn_global_load_lds(                                        \
          (const __attribute__((address_space(1))) void*)(                     \
              Bm + (size_t)(colgbase + (bt2) * 256 + it_ * 64 + colL) * DDIM + \
              (kc2) * 64 + kelemL),                                            \
          (__attribute__((address_space(3))) void*)((bufp) + it_ * 8192 +      \
                                                    wave * 1024 + lane * 16),  \
          16, 0, 0);                                                           \
    }                                                                          \
  } while (0)

// B k-slice offset within a col's 128B, swizzle folded: ((s*2+hi)^(lane&7))<<4
#define XS(s) ((((s) * 2 + hi) ^ le7) << 4)

#define CHUNK(kc, rbuf, VM, DO_ST, SBT, SKC, sbuf)                             \
  do {                                                                         \
    asm volatile("s_waitcnt vmcnt(%0)" ::"i"(VM) : "memory");                  \
    __builtin_amdgcn_s_barrier();                                              \
    const char* bP_ = (rbuf) + bbase;                                          \
    bh8 b00 = *(const bh8*)(bP_ + XS(0));                                      \
    bh8 b01 = *(const bh8*)(bP_ + 4096 + XS(0));                               \
    bh8 b10 = *(const bh8*)(bP_ + XS(1));                                      \
    bh8 b11 = *(const bh8*)(bP_ + 4096 + XS(1));                               \
    bh8 b20 = *(const bh8*)(bP_ + XS(2));                                      \
    bh8 b21 = *(const bh8*)(bP_ + 4096 + XS(2));                               \
    bh8 b30 = *(const bh8*)(bP_ + XS(3));                                      \
    bh8 b31 = *(const bh8*)(bP_ + 4096 + XS(3));                               \
    asm volatile("s_waitcnt lgkmcnt(0)" ::: "memory");                         \
    if (DO_ST) STAGE(SBT, SKC, sbuf);                                          \
    __builtin_amdgcn_sched_barrier(0);                                         \
    __builtin_amdgcn_s_setprio(1);                                             \
    acc00 = __builtin_amdgcn_mfma_f32_32x32x16_bf16(areg[0][(kc)*4+0], b00, acc00, 0,0,0); \
    acc01 = __builtin_amdgcn_mfma_f32_32x32x16_bf16(areg[0][(kc)*4+0], b01, acc01, 0,0,0); \
    acc10 = __builtin_amdgcn_mfma_f32_32x32x16_bf16(areg[1][(kc)*4+0], b00, acc10, 0,0,0); \
    acc11 = __builtin_amdgcn_mfma_f32_32x32x16_bf16(areg[1][(kc)*4+0], b01, acc11, 0,0,0); \
    acc00 = __builtin_amdgcn_mfma_f32_32x32x16_bf16(areg[0][(kc)*4+1], b10, acc00, 0,0,0); \
    acc01 = __builtin_amdgcn_mfma_f32_32x32x16_bf16(areg[0][(kc)*4+1], b11, acc01, 0,0,0); \
    acc10 = __builtin_amdgcn_mfma_f32_32x32x16_bf16(areg[1][(kc)*4+1], b10, acc10, 0,0,0); \
    acc11 = __builtin_amdgcn_mfma_f32_32x32x16_bf16(areg[1][(kc)*4+1], b11, acc11, 0,0,0); \
    acc00 = __builtin_amdgcn_mfma_f32_32x32x16_bf16(areg[0][(kc)*4+2], b20, acc00, 0,0,0); \
    acc01 = __builtin_amdgcn_mfma_f32_32x32x16_bf16(areg[0][(kc)*4+2], b21, acc01, 0,0,0); \
    acc10 = __builtin_amdgcn_mfma_f32_32x32x16_bf16(areg[1][(kc)*4+2], b20, acc10, 0,0,0); \
    acc11 = __builtin_amdgcn_mfma_f32_32x32x16_bf16(areg[1][(kc)*4+2], b21, acc11, 0,0,0); \
    acc00 = __builtin_amdgcn_mfma_f32_32x32x16_bf16(areg[0][(kc)*4+3], b30, acc00, 0,0,0); \
    acc01 = __builtin_amdgcn_mfma_f32_32x32x16_bf16(areg[0][(kc)*4+3], b31, acc01, 0,0,0); \
    acc10 = __builtin_amdgcn_mfma_f32_32x32x16_bf16(areg[1][(kc)*4+3], b30, acc10, 0,0,0); \
    acc11 = __builtin_amdgcn_mfma_f32_32x32x16_bf16(areg[1][(kc)*4+3], b31, acc11, 0,0,0); \
    __builtin_amdgcn_s_setprio(0);                                             \
  } while (0)

// per-tile epilogue for one 32x32 acc; C layout (m74/m101):
// col = lane&31, row = (reg&3) + 8*(reg>>2) + 4*(lane>>5)
#define EPI32(A_, m_, n_)                                                      \
  do {                                                                         \
    fx16 v_ = A_;                                                              \
    A_ = fzero16();                                                            \
    _Pragma("unroll")                                                          \
    for (int g_ = 0; g_ < 16; g_ += 4) {                                       \
      e0 += fexp2(k1 * v_[g_ + 0]);                                            \
      e1 += fexp2(k1 * v_[g_ + 1]);                                            \
      e2 += fexp2(k1 * v_[g_ + 2]);                                            \
      e3 += fexp2(k1 * v_[g_ + 3]);                                            \
    }                                                                          \
    if (dtile) { /* block-uniform: at most 1 of 32 tiles */                    \
      const int gcol_ = colbase + wc * 64 + (n_) * 32 + (lane & 31);           \
      const int grow0_ = rowbase + wr * 64 + (m_) * 32 + 4 * (lane >> 5);      \
      _Pragma("unroll")                                                        \
      for (int r_ = 0; r_ < 16; ++r_) {                                        \
        int grow_ = grow0_ + (r_ & 3) + 8 * (r_ >> 2);                         \
        if (grow_ == gcol_) {                                                  \
          d += softplus_f(-fmaf(scale, v_[r_], bias));                         \
          e0 -= fexp2(k1 * v_[r_]);                                            \
        }                                                                      \
      }                                                                        \
    }                                                                          \
  } while (0)

#define EPILOGUE(btv)                                                          \
  do {                                                                         \
    const int colbase = colgbase + (btv) * 256;                                \
    const bool dtile =                                                         \
        (colbase < rowbase + 128) && (rowbase < colbase + 256);                \
    EPI32(acc00, 0, 0); EPI32(acc01, 0, 1);                                    \
    EPI32(acc10, 1, 0); EPI32(acc11, 1, 1);                                    \
  } while (0)

__global__ __launch_bounds__(512, 1) void siglip_strip(
    const unsigned short* __restrict__ Am, const unsigned short* __restrict__ Bm,
    const float* __restrict__ scale_p, const float* __restrict__ bias_p,
    float* __restrict__ out) {
  extern __shared__ char smem[];
  char* q0 = smem;             // B ring: 4 x 32KB = 128KB
  char* q1 = smem + 32768;
  char* q2 = smem + 65536;
  char* q3 = smem + 98304;

  const int tid  = threadIdx.x;
  const int lane = tid & 63;
  const int wave = tid >> 6;
  const int wr   = wave >> 2;  // 0..1
  const int wc   = wave & 3;   // 0..3
  const int rp   = blockIdx.x >> 1;
  const int cg   = blockIdx.x & 1;
  const int rowbase  = rp * 128;
  const int colgbase = cg * 8192;

  // ---- per-lane constants ----
  const int hi  = lane >> 5;          // 0/1
  const int le7 = lane & 7;
  // staging: linear dest slot l*16 holds content (l*16) ^ ((l>>3)&7)<<4
  const int colL   = wave * 8 + (lane >> 3);                       // 0..63
  const int kelemL = (((lane & 7) * 16) ^ (((lane >> 3) & 7) << 4)) >> 1;
  // read base: col = wc*64 + n*32 + (lane&31), col stride 128B
  const int bbase = (wc * 64 + (lane & 31)) * 128;

  float scale = *scale_p;
  float bias  = *bias_p;
  asm volatile("" : "+v"(scale), "+v"(bias));
  const float k1 = scale * LOG2E;
  const float eb = fexp2(bias * LOG2E);  // e^bias

  // ---- prologue: A slice into registers (32 x 16B loads, static indices) --
  bh8 areg[2][16];
  {
    const unsigned short* Aw = Am + (size_t)(rowbase + wr * 64) * DDIM;
#pragma unroll
    for (int m = 0; m < 2; ++m)
#pragma unroll
      for (int ks = 0; ks < 16; ++ks)
        areg[m][ks] = *(const bh8*)(Aw + (size_t)(m * 32 + (lane & 31)) * DDIM +
                                    ks * 16 + hi * 8);
  }
  // drain A/scalar vmem so counted vmcnt below sees only staging loads
  asm volatile("s_waitcnt vmcnt(0)" ::: "memory");

  STAGE(0, 0, q0);  // chunk 0
  STAGE(0, 1, q1);  // chunk 1
  STAGE(0, 2, q2);  // chunk 2

  fx16 acc00 = fzero16(), acc01 = fzero16();
  fx16 acc10 = fzero16(), acc11 = fzero16();
  float e0 = 0.f, e1 = 0.f, e2 = 0.f, e3 = 0.f, d = 0.f;

  for (int bt = 0; bt < 31; ++bt) {
    CHUNK(0, q0, 8, 1, bt,     3, q3);
    CHUNK(1, q1, 8, 1, bt + 1, 0, q0);
    CHUNK(2, q2, 8, 1, bt + 1, 1, q1);
    CHUNK(3, q3, 8, 1, bt + 1, 2, q2);
    EPILOGUE(bt);  // register-only; overlaps MFMA drain + in-flight DMA
  }
  // ---- peeled bt = 31 (chunks 124..127) ----
  CHUNK(0, q0, 8, 1, 31, 3, q3);
  CHUNK(1, q1, 8, 0, 0, 0, q0);
  CHUNK(2, q2, 4, 0, 0, 0, q0);
  CHUNK(3, q3, 0, 0, 0, 0, q0);
  EPILOGUE(31);

  float local = fmaf((e0 + e1) + (e2 + e3), eb, d);
#pragma unroll
  for (int off = 32; off > 0; off >>= 1) local += __shfl_xor(local, off, 64);
  if (lane == 0) atomicAdd(out, local * (1.0f / 16384.0f));
}

// ===================== fallback: f32 inputs, reg-staged (no ws needed) =====
__device__ __forceinline__ unsigned swz256(unsigned o) {
  return o ^ (((o >> 8) & 7u) << 4);
}

__device__ __forceinline__ void map_tile(int bid, int& tr, int& tc) {
  int xcd = bid & 7;
  int idx = bid >> 3;
  int g   = idx >> 7;
  int w   = idx & 127;
  tr = xcd * 16 + (w >> 3);
  tc = g * 8 + (w & 7);
}

__global__ __launch_bounds__(256, 2) void siglip_fallback(
    const float* __restrict__ A, const float* __restrict__ B,
    const float* __restrict__ scale_p, const float* __restrict__ bias_p,
    float* __restrict__ out) {
  __shared__ char lds[65536];
  char* ldsA = lds;
  char* ldsB = lds + 32768;
  const int tid  = threadIdx.x;
  const int lane = tid & 63;
  const int wave = tid >> 6;
  const int wr   = wave >> 1;
  const int wc   = wave & 1;
  int tr, tc;
  map_tile(blockIdx.x, tr, tc);
  const int brow = tr * 128, bcol = tc * 128;

  fx4 acc[4][4];
#pragma unroll
  for (int m = 0; m < 4; ++m)
#pragma unroll
    for (int n = 0; n < 4; ++n) acc[m][n] = (fx4){0.f, 0.f, 0.f, 0.f};

#pragma unroll
  for (int p = 0; p < 2; ++p) {
    __syncthreads();
    const float* Af = A + (size_t)brow * DDIM + p * 128;
    const float* Bf = B + (size_t)bcol * DDIM + p * 128;
#pragma unroll
    for (int it = 0; it < 16; ++it) {
      int c = it * 256 + tid;
      int row = c >> 5, j = c & 31;
      unsigned o = row * 256 + j * 8;
      {
        float4 v = *(const float4*)(Af + (size_t)row * DDIM + j * 4);
        bh4 h;
        h[0] = f2bf(v.x); h[1] = f2bf(v.y); h[2] = f2bf(v.z); h[3] = f2bf(v.w);
        *(bh4*)(ldsA + swz256(o)) = h;
      }
      {
        float4 v = *(const float4*)(Bf + (size_t)row * DDIM + j * 4);
        bh4 h;
        h[0] = f2bf(v.x); h[1] = f2bf(v.y); h[2] = f2bf(v.z); h[3] = f2bf(v.w);
        *(bh4*)(ldsB + swz256(o)) = h;
      }
    }
    __syncthreads();
#pragma unroll
    for (int kk = 0; kk < 4; ++kk) {
      const int colb = kk * 64 + (lane >> 4) * 16;
      bh8 a[4], b[4];
#pragma unroll
      for (int m = 0; m < 4; ++m) {
        int r = wr * 64 + m * 16 + (lane & 15);
        a[m] = *(const bh8*)(ldsA + swz256((unsigned)(r * 256 + colb)));
      }
#pragma unroll
      for (int n = 0; n < 4; ++n) {
        int r = wc * 64 + n * 16 + (lane & 15);
        b[n] = *(const bh8*)(ldsB + swz256((unsigned)(r * 256 + colb)));
      }
#pragma unroll
      for (int m = 0; m < 4; ++m)
#pragma unroll
        for (int n = 0; n < 4; ++n)
          acc[m][n] = __builtin_amdgcn_mfma_f32_16x16x32_bf16(a[m], b[n],
                                                              acc[m][n], 0, 0, 0);
    }
  }

  const float scale = *scale_p;
  const float bias  = *bias_p;
  const float k1 = scale * LOG2E;
  const float k0 = bias * LOG2E;
  float s0 = 0.f, s1 = 0.f, s2 = 0.f, s3 = 0.f;
  const int  row0 = brow + wr * 64 + (lane >> 4) * 4;
  const int  col0 = bcol + wc * 64 + (lane & 15);
  const bool isdiag = (tr == tc);
#pragma unroll
  for (int m = 0; m < 4; ++m) {
#pragma unroll
    for (int n = 0; n < 4; ++n) {
      fx4 v = acc[m][n];
      s0 += fexp2(fmaf(k1, v[0], k0));
      s1 += fexp2(fmaf(k1, v[1], k0));
      s2 += fexp2(fmaf(k1, v[2], k0));
      s3 += fexp2(fmaf(k1, v[3], k0));
      if (isdiag) {
        const int gj = col0 + n * 16;
#pragma unroll
        for (int j = 0; j < 4; ++j) {
          const int gi = row0 + m * 16 + j;
          if (gi == gj) {
            float logit = fmaf(scale, v[j], bias);
            s0 += softplus_f(-logit) - fexp2(fmaf(k1, v[j], k0));
          }
        }
      }
    }
  }
  float local = (s0 + s1) + (s2 + s3);
#pragma unroll
  for (int off = 32; off > 0; off >>= 1) local += __shfl_xor(local, off, 64);

  __syncthreads();
  float* red = (float*)lds;
  if (lane == 0) red[wave] = local;
  __syncthreads();
  if (tid == 0)
    atomicAdd(out, (red[0] + red[1] + red[2] + red[3]) * (1.0f / 16384.0f));
}

extern "C" void kernel_launch(void* const* d_in, const int* in_sizes, int n_in,
                              void* d_out, int out_size, void* d_ws,
                              size_t ws_size, hipStream_t stream) {
  const float* img     = (const float*)d_in[0];
  const float* txt     = (const float*)d_in[1];
  const float* scale_p = (const float*)d_in[2];
  const float* bias_p  = (const float*)d_in[3];
  float* out = (float*)d_out;

  hipMemsetAsync(d_out, 0, (size_t)out_size * sizeof(float), stream);

  const size_t elems = (size_t)NROWS * DDIM;
  const size_t need  = 2 * elems * sizeof(unsigned short);  // 16.8 MB

  if (ws_size >= need) {
    hipError_t a3 = hipFuncSetAttribute(
        (const void*)siglip_strip,
        hipFuncAttributeMaxDynamicSharedMemorySize, 131072);
    if (a3 == hipSuccess) {
      unsigned short* Abf = (unsigned short*)d_ws;
      unsigned short* Bbf = Abf + elems;
      const int cast_blocks = (int)(elems / (256 * 8));  // 2048
      cast_bf16_kernel<<<cast_blocks, 256, 0, stream>>>(img, Abf);
      cast_bf16_kernel<<<cast_blocks, 256, 0, stream>>>(txt, Bbf);
      siglip_strip<<<256, 512, 131072, stream>>>(Abf, Bbf, scale_p, bias_p,
                                                 out);
      return;
    }
  }
  const int nblocks = (NROWS / 128) * (NROWS / 128);  // 16384
  siglip_fallback<<<nblocks, 256, 0, stream>>>(img, txt, scale_p, bias_p, out);
}

// Round 9
// 164.833 us; speedup vs baseline: 1.7268x; 1.7268x over previous
//
#include <hip/hip_runtime.h>
#include <hip/hip_bf16.h>

#define NROWS 16384
#define DDIM  256
#define LOG2E 1.44269504088896f

typedef __attribute__((ext_vector_type(8))) short bh8;    // 8 x bf16 (4 VGPR)
typedef __attribute__((ext_vector_type(4))) short bh4;
typedef __attribute__((ext_vector_type(4))) float fx4;
typedef __attribute__((ext_vector_type(16))) float fx16;  // 32x32 accumulator

__device__ __forceinline__ short f2bf(float x) {
  __hip_bfloat16 h = __float2bfloat16(x);
  return *reinterpret_cast<short*>(&h);
}

__device__ __forceinline__ float fexp2(float x) {
#if __has_builtin(__builtin_amdgcn_exp2f)
  return __builtin_amdgcn_exp2f(x);   // v_exp_f32: D = 2^S0
#else
  return __expf(x * 0.6931471805599453f);
#endif
}

__device__ __forceinline__ fx16 fzero16() {
  fx16 z;
#pragma unroll
  for (int q = 0; q < 16; ++q) z[q] = 0.f;
  return z;
}

// exact softplus, used only on the 16384 diagonal elements
__device__ __forceinline__ float softplus_f(float y) {
  float a = fabsf(y);
  float t = __expf(-a);
  float l;
  if (t < 0.125f) {
    l = t * (1.0f - t * (0.5f - 0.333333333f * t));
  } else {
    l = log1pf(t);
  }
  return fmaxf(y, 0.0f) + l;
}

__global__ void cast_bf16_kernel(const float* __restrict__ in,
                                 unsigned short* __restrict__ out) {
  int i = (blockIdx.x * blockDim.x + threadIdx.x) * 8;
  float4 v0 = *(const float4*)(in + i);
  float4 v1 = *(const float4*)(in + i + 4);
  bh8 o;
  o[0] = f2bf(v0.x); o[1] = f2bf(v0.y); o[2] = f2bf(v0.z); o[3] = f2bf(v0.w);
  o[4] = f2bf(v1.x); o[5] = f2bf(v1.y); o[6] = f2bf(v1.z); o[7] = f2bf(v1.w);
  *(bh8*)((unsigned short*)out + i) = o;
}

// ============ persistent strip kernel: A-in-registers, 256-thread =========
// 512 blocks (2/CU), 256 threads = 4 waves (2 wr x 2 wc), wave tile 64x64 of
// mfma_f32_32x32x16_bf16 (2x2 fx16). Block = 128 img rows x 4096 txt cols
// (cg 0..3). A slice (64 rows x 256 k per wave) resident in 128 VGPRs
// (areg[2][16], static indices). LDS = 64KB static: B ring 4 x 16KB; chunk =
// 128 cols x 64 k. Single barrier per chunk; counted vmcnt(8); stage(t+3)
// into the buffer freed by chunk t-1 (WAR-safe: every wave's reads of that
// buffer completed at its own lgkmcnt(0) before it reached this barrier).
// R7/R8 lesson: 512-thread blocks pinned arch-VGPR at 128 under every
// launch_bounds variant -> spill. 256-thread blocks have the m97 precedent
// (164 arch + 64 agpr) and unambiguous (256, k=blocks/CU) semantics.

// stage chunk (bt2,kc2) into buffer bufp (4 x global_load_lds / thread)
#define STAGE(bt2, kc2, bufp)                                                  \
  do {                                                                         \
    _Pragma("unroll")                                                          \
    for (int it_ = 0; it_ < 4; ++it_) {                                        \
      __builtin_amdgcn_global_load_lds(                                        \
          (const __attribute__((address_space(1))) void*)(                     \
              Bm + (size_t)(colgbase + (bt2) * 128 + it_ * 32 + colL) * DDIM + \
              (kc2) * 64 + kelemL),                                            \
          (__attribute__((address_space(3))) void*)((bufp) + it_ * 4096 +      \
                                                    wave * 1024 + lane * 16),  \
          16, 0, 0);                                                           \
    }                                                                          \
  } while (0)

// B k-slice offset within a col's 128B, swizzle folded: ((s*2+hi)^(lane&7))<<4
#define XS(s) ((((s) * 2 + hi) ^ le7) << 4)

#define MFMA8(ks)                                                              \
  do {                                                                         \
    __builtin_amdgcn_s_setprio(1);                                             \
    acc00 = __builtin_amdgcn_mfma_f32_32x32x16_bf16(areg[0][(ks)], bA, acc00, 0,0,0); \
    acc01 = __builtin_amdgcn_mfma_f32_32x32x16_bf16(areg[0][(ks)], bB, acc01, 0,0,0); \
    acc10 = __builtin_amdgcn_mfma_f32_32x32x16_bf16(areg[1][(ks)], bA, acc10, 0,0,0); \
    acc11 = __builtin_amdgcn_mfma_f32_32x32x16_bf16(areg[1][(ks)], bB, acc11, 0,0,0); \
    acc00 = __builtin_amdgcn_mfma_f32_32x32x16_bf16(areg[0][(ks)+1], bC, acc00, 0,0,0); \
    acc01 = __builtin_amdgcn_mfma_f32_32x32x16_bf16(areg[0][(ks)+1], bD, acc01, 0,0,0); \
    acc10 = __builtin_amdgcn_mfma_f32_32x32x16_bf16(areg[1][(ks)+1], bC, acc10, 0,0,0); \
    acc11 = __builtin_amdgcn_mfma_f32_32x32x16_bf16(areg[1][(ks)+1], bD, acc11, 0,0,0); \
    __builtin_amdgcn_s_setprio(0);                                             \
  } while (0)

#define CHUNK(kc, rbuf, VM, DO_ST, SBT, SKC, sbuf)                             \
  do {                                                                         \
    asm volatile("s_waitcnt vmcnt(%0)" ::"i"(VM) : "memory");                  \
    __builtin_amdgcn_s_barrier();                                              \
    const char* bP_ = (rbuf) + bbase;                                          \
    bh8 bA, bB, bC, bD;                                                        \
    /* group 0: k-slices 0,1 */                                                \
    bA = *(const bh8*)(bP_ + XS(0));                                           \
    bB = *(const bh8*)(bP_ + 4096 + XS(0));                                    \
    bC = *(const bh8*)(bP_ + XS(1));                                           \
    bD = *(const bh8*)(bP_ + 4096 + XS(1));                                    \
    asm volatile("s_waitcnt lgkmcnt(0)" ::: "memory");                         \
    if (DO_ST) STAGE(SBT, SKC, sbuf);                                          \
    __builtin_amdgcn_sched_barrier(0);                                         \
    MFMA8((kc) * 4 + 0);                                                       \
    /* group 1: k-slices 2,3 (same buffer, no barrier needed) */               \
    bA = *(const bh8*)(bP_ + XS(2));                                           \
    bB = *(const bh8*)(bP_ + 4096 + XS(2));                                    \
    bC = *(const bh8*)(bP_ + XS(3));                                           \
    bD = *(const bh8*)(bP_ + 4096 + XS(3));                                    \
    asm volatile("s_waitcnt lgkmcnt(0)" ::: "memory");                         \
    __builtin_amdgcn_sched_barrier(0);                                         \
    MFMA8((kc) * 4 + 2);                                                       \
  } while (0)

// per-tile epilogue for one 32x32 acc; C layout (m74/m101):
// col = lane&31, row = (reg&3) + 8*(reg>>2) + 4*(lane>>5)
#define EPI32(A_, m_, n_)                                                      \
  do {                                                                         \
    fx16 v_ = A_;                                                              \
    A_ = fzero16();                                                            \
    _Pragma("unroll")                                                          \
    for (int g_ = 0; g_ < 16; g_ += 4) {                                       \
      e0 += fexp2(k1 * v_[g_ + 0]);                                            \
      e1 += fexp2(k1 * v_[g_ + 1]);                                            \
      e2 += fexp2(k1 * v_[g_ + 2]);                                            \
      e3 += fexp2(k1 * v_[g_ + 3]);                                            \
    }                                                                          \
    if (dtile) { /* block-uniform: at most 1 of 32 tiles */                    \
      const int gcol_ = colbase + wc * 64 + (n_) * 32 + (lane & 31);           \
      const int grow0_ = rowbase + wr * 64 + (m_) * 32 + 4 * hi;               \
      _Pragma("unroll")                                                        \
      for (int r_ = 0; r_ < 16; ++r_) {                                        \
        int grow_ = grow0_ + (r_ & 3) + 8 * (r_ >> 2);                         \
        if (grow_ == gcol_) {                                                  \
          d += softplus_f(-fmaf(scale, v_[r_], bias));                         \
          e0 -= fexp2(k1 * v_[r_]);                                            \
        }                                                                      \
      }                                                                        \
    }                                                                          \
  } while (0)

#define EPILOGUE(btv)                                                          \
  do {                                                                         \
    const int colbase = colgbase + (btv) * 128;                                \
    const bool dtile = (colbase == rowbase);                                   \
    EPI32(acc00, 0, 0); EPI32(acc01, 0, 1);                                    \
    EPI32(acc10, 1, 0); EPI32(acc11, 1, 1);                                    \
  } while (0)

__global__ __launch_bounds__(256, 2) void siglip_strip(
    const unsigned short* __restrict__ Am, const unsigned short* __restrict__ Bm,
    const float* __restrict__ scale_p, const float* __restrict__ bias_p,
    float* __restrict__ out) {
  __shared__ char lds[65536];    // B ring: 4 x 16KB
  char* q0 = lds;
  char* q1 = lds + 16384;
  char* q2 = lds + 32768;
  char* q3 = lds + 49152;

  const int tid  = threadIdx.x;
  const int lane = tid & 63;
  const int wave = tid >> 6;     // 0..3
  const int wr   = wave >> 1;    // 0..1
  const int wc   = wave & 1;     // 0..1
  // XCD-aware mapping: cg fixed per XCD pair (bid&7 = XCD on dispatch).
  const int bid  = blockIdx.x;
  const int rp   = ((bid >> 3) << 1) | (bid & 1);  // 0..127
  const int cg   = (bid >> 1) & 3;                 // 0..3
  const int rowbase  = rp * 128;
  const int colgbase = cg * 4096;

  // ---- per-lane constants ----
  const int hi  = lane >> 5;          // 0/1
  const int le7 = lane & 7;
  // staging: linear dest slot l*16 holds content (l*16) ^ ((l>>3)&7)<<4
  const int colL   = wave * 8 + (lane >> 3);                       // 0..31
  const int kelemL = (((lane & 7) * 16) ^ (((lane >> 3) & 7) << 4)) >> 1;
  // read base: col = wc*64 + n*32 + (lane&31), col stride 128B
  const int bbase = (wc * 64 + (lane & 31)) * 128;

  float scale = *scale_p;
  float bias  = *bias_p;
  asm volatile("" : "+v"(scale), "+v"(bias));
  const float k1 = scale * LOG2E;
  const float eb = fexp2(bias * LOG2E);  // e^bias

  // ---- prologue: A slice into registers (32 x 16B loads, static indices) --
  bh8 areg[2][16];
  {
    const unsigned short* Aw = Am + (size_t)(rowbase + wr * 64) * DDIM;
#pragma unroll
    for (int m = 0; m < 2; ++m)
#pragma unroll
      for (int ks = 0; ks < 16; ++ks)
        areg[m][ks] = *(const bh8*)(Aw + (size_t)(m * 32 + (lane & 31)) * DDIM +
                                    ks * 16 + hi * 8);
  }
  // drain A/scalar vmem so counted vmcnt below sees only staging loads
  asm volatile("s_waitcnt vmcnt(0)" ::: "memory");

  STAGE(0, 0, q0);  // chunk 0
  STAGE(0, 1, q1);  // chunk 1
  STAGE(0, 2, q2);  // chunk 2

  fx16 acc00 = fzero16(), acc01 = fzero16();
  fx16 acc10 = fzero16(), acc11 = fzero16();
  float e0 = 0.f, e1 = 0.f, e2 = 0.f, e3 = 0.f, d = 0.f;

  for (int bt = 0; bt < 31; ++bt) {
    CHUNK(0, q0, 8, 1, bt,     3, q3);
    CHUNK(1, q1, 8, 1, bt + 1, 0, q0);
    CHUNK(2, q2, 8, 1, bt + 1, 1, q1);
    CHUNK(3, q3, 8, 1, bt + 1, 2, q2);
    EPILOGUE(bt);  // register-only; overlaps MFMA drain + in-flight DMA
  }
  // ---- peeled bt = 31 (chunks 124..127) ----
  CHUNK(0, q0, 8, 1, 31, 3, q3);
  CHUNK(1, q1, 8, 0, 0, 0, q0);
  CHUNK(2, q2, 4, 0, 0, 0, q0);
  CHUNK(3, q3, 0, 0, 0, 0, q0);
  EPILOGUE(31);

  float local = fmaf((e0 + e1) + (e2 + e3), eb, d);
#pragma unroll
  for (int off = 32; off > 0; off >>= 1) local += __shfl_xor(local, off, 64);

  __syncthreads();  // LDS reuse for block reduction
  float* red = (float*)lds;
  if (lane == 0) red[wave] = local;
  __syncthreads();
  if (tid == 0)
    atomicAdd(out, ((red[0] + red[1]) + (red[2] + red[3])) * (1.0f / 16384.0f));
}

// ===================== fallback: f32 inputs, reg-staged (no ws needed) =====
__device__ __forceinline__ unsigned swz256(unsigned o) {
  return o ^ (((o >> 8) & 7u) << 4);
}

__device__ __forceinline__ void map_tile(int bid, int& tr, int& tc) {
  int xcd = bid & 7;
  int idx = bid >> 3;
  int g   = idx >> 7;
  int w   = idx & 127;
  tr = xcd * 16 + (w >> 3);
  tc = g * 8 + (w & 7);
}

__global__ __launch_bounds__(256, 2) void siglip_fallback(
    const float* __restrict__ A, const float* __restrict__ B,
    const float* __restrict__ scale_p, const float* __restrict__ bias_p,
    float* __restrict__ out) {
  __shared__ char lds[65536];
  char* ldsA = lds;
  char* ldsB = lds + 32768;
  const int tid  = threadIdx.x;
  const int lane = tid & 63;
  const int wave = tid >> 6;
  const int wr   = wave >> 1;
  const int wc   = wave & 1;
  int tr, tc;
  map_tile(blockIdx.x, tr, tc);
  const int brow = tr * 128, bcol = tc * 128;

  fx4 acc[4][4];
#pragma unroll
  for (int m = 0; m < 4; ++m)
#pragma unroll
    for (int n = 0; n < 4; ++n) acc[m][n] = (fx4){0.f, 0.f, 0.f, 0.f};

#pragma unroll
  for (int p = 0; p < 2; ++p) {
    __syncthreads();
    const float* Af = A + (size_t)brow * DDIM + p * 128;
    const float* Bf = B + (size_t)bcol * DDIM + p * 128;
#pragma unroll
    for (int it = 0; it < 16; ++it) {
      int c = it * 256 + tid;
      int row = c >> 5, j = c & 31;
      unsigned o = row * 256 + j * 8;
      {
        float4 v = *(const float4*)(Af + (size_t)row * DDIM + j * 4);
        bh4 h;
        h[0] = f2bf(v.x); h[1] = f2bf(v.y); h[2] = f2bf(v.z); h[3] = f2bf(v.w);
        *(bh4*)(ldsA + swz256(o)) = h;
      }
      {
        float4 v = *(const float4*)(Bf + (size_t)row * DDIM + j * 4);
        bh4 h;
        h[0] = f2bf(v.x); h[1] = f2bf(v.y); h[2] = f2bf(v.z); h[3] = f2bf(v.w);
        *(bh4*)(ldsB + swz256(o)) = h;
      }
    }
    __syncthreads();
#pragma unroll
    for (int kk = 0; kk < 4; ++kk) {
      const int colb = kk * 64 + (lane >> 4) * 16;
      bh8 a[4], b[4];
#pragma unroll
      for (int m = 0; m < 4; ++m) {
        int r = wr * 64 + m * 16 + (lane & 15);
        a[m] = *(const bh8*)(ldsA + swz256((unsigned)(r * 256 + colb)));
      }
#pragma unroll
      for (int n = 0; n < 4; ++n) {
        int r = wc * 64 + n * 16 + (lane & 15);
        b[n] = *(const bh8*)(ldsB + swz256((unsigned)(r * 256 + colb)));
      }
#pragma unroll
      for (int m = 0; m < 4; ++m)
#pragma unroll
        for (int n = 0; n < 4; ++n)
          acc[m][n] = __builtin_amdgcn_mfma_f32_16x16x32_bf16(a[m], b[n],
                                                              acc[m][n], 0, 0, 0);
    }
  }

  const float scale = *scale_p;
  const float bias  = *bias_p;
  const float k1 = scale * LOG2E;
  const float k0 = bias * LOG2E;
  float s0 = 0.f, s1 = 0.f, s2 = 0.f, s3 = 0.f;
  const int  row0 = brow + wr * 64 + (lane >> 4) * 4;
  const int  col0 = bcol + wc * 64 + (lane & 15);
  const bool isdiag = (tr == tc);
#pragma unroll
  for (int m = 0; m < 4; ++m) {
#pragma unroll
    for (int n = 0; n < 4; ++n) {
      fx4 v = acc[m][n];
      s0 += fexp2(fmaf(k1, v[0], k0));
      s1 += fexp2(fmaf(k1, v[1], k0));
      s2 += fexp2(fmaf(k1, v[2], k0));
      s3 += fexp2(fmaf(k1, v[3], k0));
      if (isdiag) {
        const int gj = col0 + n * 16;
#pragma unroll
        for (int j = 0; j < 4; ++j) {
          const int gi = row0 + m * 16 + j;
          if (gi == gj) {
            float logit = fmaf(scale, v[j], bias);
            s0 += softplus_f(-logit) - fexp2(fmaf(k1, v[j], k0));
          }
        }
      }
    }
  }
  float local = (s0 + s1) + (s2 + s3);
#pragma unroll
  for (int off = 32; off > 0; off >>= 1) local += __shfl_xor(local, off, 64);

  __syncthreads();
  float* red = (float*)lds;
  if (lane == 0) red[wave] = local;
  __syncthreads();
  if (tid == 0)
    atomicAdd(out, (red[0] + red[1] + red[2] + red[3]) * (1.0f / 16384.0f));
}

extern "C" void kernel_launch(void* const* d_in, const int* in_sizes, int n_in,
                              void* d_out, int out_size, void* d_ws,
                              size_t ws_size, hipStream_t stream) {
  const float* img     = (const float*)d_in[0];
  const float* txt     = (const float*)d_in[1];
  const float* scale_p = (const float*)d_in[2];
  const float* bias_p  = (const float*)d_in[3];
  float* out = (float*)d_out;

  hipMemsetAsync(d_out, 0, (size_t)out_size * sizeof(float), stream);

  const size_t elems = (size_t)NROWS * DDIM;
  const size_t need  = 2 * elems * sizeof(unsigned short);  // 16.8 MB

  if (ws_size >= need) {
    unsigned short* Abf = (unsigned short*)d_ws;
    unsigned short* Bbf = Abf + elems;
    const int cast_blocks = (int)(elems / (256 * 8));  // 2048
    cast_bf16_kernel<<<cast_blocks, 256, 0, stream>>>(img, Abf);
    cast_bf16_kernel<<<cast_blocks, 256, 0, stream>>>(txt, Bbf);
    siglip_strip<<<512, 256, 0, stream>>>(Abf, Bbf, scale_p, bias_p, out);
    return;
  }
  const int nblocks = (NROWS / 128) * (NROWS / 128);  // 16384
  siglip_fallback<<<nblocks, 256, 0, stream>>>(img, txt, scale_p, bias_p, out);
}

// Round 10
// 147.792 us; speedup vs baseline: 1.9259x; 1.1153x over previous
//
#include <hip/hip_runtime.h>
#include <hip/hip_bf16.h>

#define NROWS 16384
#define DDIM  256
#define LOG2E 1.44269504088896f

typedef __attribute__((ext_vector_type(8))) short bh8;    // 8 x bf16 (4 VGPR)
typedef __attribute__((ext_vector_type(4))) short bh4;
typedef __attribute__((ext_vector_type(4))) float fx4;
typedef __attribute__((ext_vector_type(16))) float fx16;  // 32x32 accumulator

__device__ __forceinline__ short f2bf(float x) {
  __hip_bfloat16 h = __float2bfloat16(x);
  return *reinterpret_cast<short*>(&h);
}

__device__ __forceinline__ float fexp2(float x) {
#if __has_builtin(__builtin_amdgcn_exp2f)
  return __builtin_amdgcn_exp2f(x);   // v_exp_f32: D = 2^S0
#else
  return __expf(x * 0.6931471805599453f);
#endif
}

__device__ __forceinline__ fx16 fzero16() {
  fx16 z;
#pragma unroll
  for (int q = 0; q < 16; ++q) z[q] = 0.f;
  return z;
}

// exact softplus, used only on the 16384 diagonal elements
__device__ __forceinline__ float softplus_f(float y) {
  float a = fabsf(y);
  float t = __expf(-a);
  float l;
  if (t < 0.125f) {
    l = t * (1.0f - t * (0.5f - 0.333333333f * t));
  } else {
    l = log1pf(t);
  }
  return fmaxf(y, 0.0f) + l;
}

__global__ void cast_bf16_kernel(const float* __restrict__ in,
                                 unsigned short* __restrict__ out) {
  int i = (blockIdx.x * blockDim.x + threadIdx.x) * 8;
  float4 v0 = *(const float4*)(in + i);
  float4 v1 = *(const float4*)(in + i + 4);
  bh8 o;
  o[0] = f2bf(v0.x); o[1] = f2bf(v0.y); o[2] = f2bf(v0.z); o[3] = f2bf(v0.w);
  o[4] = f2bf(v1.x); o[5] = f2bf(v1.y); o[6] = f2bf(v1.z); o[7] = f2bf(v1.w);
  *(bh8*)((unsigned short*)out + i) = o;
}

// ============ persistent strip kernel: A-in-registers, 256-thread =========
// 512 blocks (2/CU), 256 threads = 4 waves (2 wr x 2 wc), wave tile 64x64 of
// mfma_f32_32x32x16_bf16 (2x2 fx16). Block = 128 img rows x 4096 txt cols.
// A slice resident in 128 regs/wave (areg[2][16], static indices). LDS =
// 64KB static: B ring 4 x 16KB; chunk = 128 cols x 64 k; stage(t+3) into the
// buffer freed by chunk t-1; counted vmcnt(8) once per chunk.
// R9->R10: removed ALL manual lgkmcnt(0)/sched_barrier(0)/setprio. The only
// fences kept are correctness-critical: counted vmcnt before the barrier
// (each wave's own stage retired; barrier makes it collective) and an empty
// asm-memory fence after the barrier (ds_reads must not hoist above it —
// per-wave vmcnt does not cover other waves' DMA). The compiler then emits
// its own counted lgkm waits and pipelines reads under MFMAs (m97/m141).

// stage chunk (bt2,kc2) into buffer bufp (4 x global_load_lds / thread)
#define STAGE(bt2, kc2, bufp)                                                  \
  do {                                                                         \
    _Pragma("unroll")                                                          \
    for (int it_ = 0; it_ < 4; ++it_) {                                        \
      __builtin_amdgcn_global_load_lds(                                        \
          (const __attribute__((address_space(1))) void*)(                     \
              Bm + (size_t)(colgbase + (bt2) * 128 + it_ * 32 + colL) * DDIM + \
              (kc2) * 64 + kelemL),                                            \
          (__attribute__((address_space(3))) void*)((bufp) + it_ * 4096 +      \
                                                    wave * 1024 + lane * 16),  \
          16, 0, 0);                                                           \
    }                                                                          \
  } while (0)

// B k-slice offset within a col's 128B, swizzle folded: ((s*2+hi)^(lane&7))<<4
#define XS(s) ((((s) * 2 + hi) ^ le7) << 4)

#define CHUNK(kc, rbuf, VM, DO_ST, SBT, SKC, sbuf)                             \
  do {                                                                         \
    asm volatile("s_waitcnt vmcnt(%0)" ::"i"(VM) : "memory");                  \
    __builtin_amdgcn_s_barrier();                                              \
    asm volatile("" ::: "memory"); /* no LDS reads above the barrier */        \
    const char* bP_ = (rbuf) + bbase;                                          \
    bh8 b0A = *(const bh8*)(bP_ + XS(0));                                      \
    bh8 b0B = *(const bh8*)(bP_ + 4096 + XS(0));                               \
    bh8 b1A = *(const bh8*)(bP_ + XS(1));                                      \
    bh8 b1B = *(const bh8*)(bP_ + 4096 + XS(1));                               \
    bh8 b2A = *(const bh8*)(bP_ + XS(2));                                      \
    bh8 b2B = *(const bh8*)(bP_ + 4096 + XS(2));                               \
    bh8 b3A = *(const bh8*)(bP_ + XS(3));                                      \
    bh8 b3B = *(const bh8*)(bP_ + 4096 + XS(3));                               \
    if (DO_ST) STAGE(SBT, SKC, sbuf);                                          \
    acc00 = __builtin_amdgcn_mfma_f32_32x32x16_bf16(areg[0][(kc)*4+0], b0A, acc00, 0,0,0); \
    acc01 = __builtin_amdgcn_mfma_f32_32x32x16_bf16(areg[0][(kc)*4+0], b0B, acc01, 0,0,0); \
    acc10 = __builtin_amdgcn_mfma_f32_32x32x16_bf16(areg[1][(kc)*4+0], b0A, acc10, 0,0,0); \
    acc11 = __builtin_amdgcn_mfma_f32_32x32x16_bf16(areg[1][(kc)*4+0], b0B, acc11, 0,0,0); \
    acc00 = __builtin_amdgcn_mfma_f32_32x32x16_bf16(areg[0][(kc)*4+1], b1A, acc00, 0,0,0); \
    acc01 = __builtin_amdgcn_mfma_f32_32x32x16_bf16(areg[0][(kc)*4+1], b1B, acc01, 0,0,0); \
    acc10 = __builtin_amdgcn_mfma_f32_32x32x16_bf16(areg[1][(kc)*4+1], b1A, acc10, 0,0,0); \
    acc11 = __builtin_amdgcn_mfma_f32_32x32x16_bf16(areg[1][(kc)*4+1], b1B, acc11, 0,0,0); \
    acc00 = __builtin_amdgcn_mfma_f32_32x32x16_bf16(areg[0][(kc)*4+2], b2A, acc00, 0,0,0); \
    acc01 = __builtin_amdgcn_mfma_f32_32x32x16_bf16(areg[0][(kc)*4+2], b2B, acc01, 0,0,0); \
    acc10 = __builtin_amdgcn_mfma_f32_32x32x16_bf16(areg[1][(kc)*4+2], b2A, acc10, 0,0,0); \
    acc11 = __builtin_amdgcn_mfma_f32_32x32x16_bf16(areg[1][(kc)*4+2], b2B, acc11, 0,0,0); \
    acc00 = __builtin_amdgcn_mfma_f32_32x32x16_bf16(areg[0][(kc)*4+3], b3A, acc00, 0,0,0); \
    acc01 = __builtin_amdgcn_mfma_f32_32x32x16_bf16(areg[0][(kc)*4+3], b3B, acc01, 0,0,0); \
    acc10 = __builtin_amdgcn_mfma_f32_32x32x16_bf16(areg[1][(kc)*4+3], b3A, acc10, 0,0,0); \
    acc11 = __builtin_amdgcn_mfma_f32_32x32x16_bf16(areg[1][(kc)*4+3], b3B, acc11, 0,0,0); \
  } while (0)

// per-tile epilogue for one 32x32 acc; C layout (m74/m101):
// col = lane&31, row = (reg&3) + 8*(reg>>2) + 4*(lane>>5)
#define EPI32(A_, m_, n_)                                                      \
  do {                                                                         \
    fx16 v_ = A_;                                                              \
    A_ = fzero16();                                                            \
    _Pragma("unroll")                                                          \
    for (int g_ = 0; g_ < 16; g_ += 4) {                                       \
      e0 += fexp2(k1 * v_[g_ + 0]);                                            \
      e1 += fexp2(k1 * v_[g_ + 1]);                                            \
      e2 += fexp2(k1 * v_[g_ + 2]);                                            \
      e3 += fexp2(k1 * v_[g_ + 3]);                                            \
    }                                                                          \
    if (dtile) { /* block-uniform: at most 1 of 32 tiles */                    \
      const int gcol_ = colbase + wc * 64 + (n_) * 32 + (lane & 31);           \
      const int grow0_ = rowbase + wr * 64 + (m_) * 32 + 4 * hi;               \
      _Pragma("unroll")                                                        \
      for (int r_ = 0; r_ < 16; ++r_) {                                        \
        int grow_ = grow0_ + (r_ & 3) + 8 * (r_ >> 2);                         \
        if (grow_ == gcol_) {                                                  \
          d += softplus_f(-fmaf(scale, v_[r_], bias));                         \
          e0 -= fexp2(k1 * v_[r_]);                                            \
        }                                                                      \
      }                                                                        \
    }                                                                          \
  } while (0)

#define EPILOGUE(btv)                                                          \
  do {                                                                         \
    const int colbase = colgbase + (btv) * 128;                                \
    const bool dtile = (colbase == rowbase);                                   \
    EPI32(acc00, 0, 0); EPI32(acc01, 0, 1);                                    \
    EPI32(acc10, 1, 0); EPI32(acc11, 1, 1);                                    \
  } while (0)

__global__ __launch_bounds__(256, 2) void siglip_strip(
    const unsigned short* __restrict__ Am, const unsigned short* __restrict__ Bm,
    const float* __restrict__ scale_p, const float* __restrict__ bias_p,
    float* __restrict__ out) {
  __shared__ char lds[65536];    // B ring: 4 x 16KB
  char* q0 = lds;
  char* q1 = lds + 16384;
  char* q2 = lds + 32768;
  char* q3 = lds + 49152;

  const int tid  = threadIdx.x;
  const int lane = tid & 63;
  const int wave = tid >> 6;     // 0..3
  const int wr   = wave >> 1;    // 0..1
  const int wc   = wave & 1;     // 0..1
  // XCD-aware mapping: cg fixed per XCD (bid&7 = XCD on dispatch).
  const int bid  = blockIdx.x;
  const int rp   = ((bid >> 3) << 1) | (bid & 1);  // 0..127
  const int cg   = (bid >> 1) & 3;                 // 0..3
  const int rowbase  = rp * 128;
  const int colgbase = cg * 4096;

  // ---- per-lane constants ----
  const int hi  = lane >> 5;          // 0/1
  const int le7 = lane & 7;
  // staging: linear dest slot l*16 holds content (l*16) ^ ((l>>3)&7)<<4
  const int colL   = wave * 8 + (lane >> 3);                       // 0..31
  const int kelemL = (((lane & 7) * 16) ^ (((lane >> 3) & 7) << 4)) >> 1;
  // read base: col = wc*64 + n*32 + (lane&31), col stride 128B
  const int bbase = (wc * 64 + (lane & 31)) * 128;

  const float scale = *scale_p;   // uniform -> SGPR (lgkm domain)
  const float bias  = *bias_p;
  const float k1 = scale * LOG2E;
  const float eb = fexp2(bias * LOG2E);  // e^bias

  // ---- prologue: A slice into registers (32 x 16B loads, static indices) --
  bh8 areg[2][16];
  {
    const unsigned short* Aw = Am + (size_t)(rowbase + wr * 64) * DDIM;
#pragma unroll
    for (int m = 0; m < 2; ++m)
#pragma unroll
      for (int ks = 0; ks < 16; ++ks)
        areg[m][ks] = *(const bh8*)(Aw + (size_t)(m * 32 + (lane & 31)) * DDIM +
                                    ks * 16 + hi * 8);
  }
  // drain all prologue vmem so counted vmcnt below sees only staging loads
  asm volatile("s_waitcnt vmcnt(0)" ::: "memory");

  STAGE(0, 0, q0);  // chunk 0
  STAGE(0, 1, q1);  // chunk 1
  STAGE(0, 2, q2);  // chunk 2

  fx16 acc00 = fzero16(), acc01 = fzero16();
  fx16 acc10 = fzero16(), acc11 = fzero16();
  float e0 = 0.f, e1 = 0.f, e2 = 0.f, e3 = 0.f, d = 0.f;

  for (int bt = 0; bt < 31; ++bt) {
    CHUNK(0, q0, 8, 1, bt,     3, q3);
    CHUNK(1, q1, 8, 1, bt + 1, 0, q0);
    CHUNK(2, q2, 8, 1, bt + 1, 1, q1);
    CHUNK(3, q3, 8, 1, bt + 1, 2, q2);
    EPILOGUE(bt);  // register-only; free to sink under later chunks
  }
  // ---- peeled bt = 31 (chunks 124..127) ----
  CHUNK(0, q0, 8, 1, 31, 3, q3);
  CHUNK(1, q1, 8, 0, 0, 0, q0);
  CHUNK(2, q2, 4, 0, 0, 0, q0);
  CHUNK(3, q3, 0, 0, 0, 0, q0);
  EPILOGUE(31);

  float local = fmaf((e0 + e1) + (e2 + e3), eb, d);
#pragma unroll
  for (int off = 32; off > 0; off >>= 1) local += __shfl_xor(local, off, 64);

  __syncthreads();  // LDS reuse for block reduction
  float* red = (float*)lds;
  if (lane == 0) red[wave] = local;
  __syncthreads();
  if (tid == 0)
    atomicAdd(out, ((red[0] + red[1]) + (red[2] + red[3])) * (1.0f / 16384.0f));
}

// ===================== fallback: f32 inputs, reg-staged (no ws needed) =====
__device__ __forceinline__ unsigned swz256(unsigned o) {
  return o ^ (((o >> 8) & 7u) << 4);
}

__device__ __forceinline__ void map_tile(int bid, int& tr, int& tc) {
  int xcd = bid & 7;
  int idx = bid >> 3;
  int g   = idx >> 7;
  int w   = idx & 127;
  tr = xcd * 16 + (w >> 3);
  tc = g * 8 + (w & 7);
}

__global__ __launch_bounds__(256, 2) void siglip_fallback(
    const float* __restrict__ A, const float* __restrict__ B,
    const float* __restrict__ scale_p, const float* __restrict__ bias_p,
    float* __restrict__ out) {
  __shared__ char lds[65536];
  char* ldsA = lds;
  char* ldsB = lds + 32768;
  const int tid  = threadIdx.x;
  const int lane = tid & 63;
  const int wave = tid >> 6;
  const int wr   = wave >> 1;
  const int wc   = wave & 1;
  int tr, tc;
  map_tile(blockIdx.x, tr, tc);
  const int brow = tr * 128, bcol = tc * 128;

  fx4 acc[4][4];
#pragma unroll
  for (int m = 0; m < 4; ++m)
#pragma unroll
    for (int n = 0; n < 4; ++n) acc[m][n] = (fx4){0.f, 0.f, 0.f, 0.f};

#pragma unroll
  for (int p = 0; p < 2; ++p) {
    __syncthreads();
    const float* Af = A + (size_t)brow * DDIM + p * 128;
    const float* Bf = B + (size_t)bcol * DDIM + p * 128;
#pragma unroll
    for (int it = 0; it < 16; ++it) {
      int c = it * 256 + tid;
      int row = c >> 5, j = c & 31;
      unsigned o = row * 256 + j * 8;
      {
        float4 v = *(const float4*)(Af + (size_t)row * DDIM + j * 4);
        bh4 h;
        h[0] = f2bf(v.x); h[1] = f2bf(v.y); h[2] = f2bf(v.z); h[3] = f2bf(v.w);
        *(bh4*)(ldsA + swz256(o)) = h;
      }
      {
        float4 v = *(const float4*)(Bf + (size_t)row * DDIM + j * 4);
        bh4 h;
        h[0] = f2bf(v.x); h[1] = f2bf(v.y); h[2] = f2bf(v.z); h[3] = f2bf(v.w);
        *(bh4*)(ldsB + swz256(o)) = h;
      }
    }
    __syncthreads();
#pragma unroll
    for (int kk = 0; kk < 4; ++kk) {
      const int colb = kk * 64 + (lane >> 4) * 16;
      bh8 a[4], b[4];
#pragma unroll
      for (int m = 0; m < 4; ++m) {
        int r = wr * 64 + m * 16 + (lane & 15);
        a[m] = *(const bh8*)(ldsA + swz256((unsigned)(r * 256 + colb)));
      }
#pragma unroll
      for (int n = 0; n < 4; ++n) {
        int r = wc * 64 + n * 16 + (lane & 15);
        b[n] = *(const bh8*)(ldsB + swz256((unsigned)(r * 256 + colb)));
      }
#pragma unroll
      for (int m = 0; m < 4; ++m)
#pragma unroll
        for (int n = 0; n < 4; ++n)
          acc[m][n] = __builtin_amdgcn_mfma_f32_16x16x32_bf16(a[m], b[n],
                                                              acc[m][n], 0, 0, 0);
    }
  }

  const float scale = *scale_p;
  const float bias  = *bias_p;
  const float k1 = scale * LOG2E;
  const float k0 = bias * LOG2E;
  float s0 = 0.f, s1 = 0.f, s2 = 0.f, s3 = 0.f;
  const int  row0 = brow + wr * 64 + (lane >> 4) * 4;
  const int  col0 = bcol + wc * 64 + (lane & 15);
  const bool isdiag = (tr == tc);
#pragma unroll
  for (int m = 0; m < 4; ++m) {
#pragma unroll
    for (int n = 0; n < 4; ++n) {
      fx4 v = acc[m][n];
      s0 += fexp2(fmaf(k1, v[0], k0));
      s1 += fexp2(fmaf(k1, v[1], k0));
      s2 += fexp2(fmaf(k1, v[2], k0));
      s3 += fexp2(fmaf(k1, v[3], k0));
      if (isdiag) {
        const int gj = col0 + n * 16;
#pragma unroll
        for (int j = 0; j < 4; ++j) {
          const int gi = row0 + m * 16 + j;
          if (gi == gj) {
            float logit = fmaf(scale, v[j], bias);
            s0 += softplus_f(-logit) - fexp2(fmaf(k1, v[j], k0));
          }
        }
      }
    }
  }
  float local = (s0 + s1) + (s2 + s3);
#pragma unroll
  for (int off = 32; off > 0; off >>= 1) local += __shfl_xor(local, off, 64);

  __syncthreads();
  float* red = (float*)lds;
  if (lane == 0) red[wave] = local;
  __syncthreads();
  if (tid == 0)
    atomicAdd(out, (red[0] + red[1] + red[2] + red[3]) * (1.0f / 16384.0f));
}

extern "C" void kernel_launch(void* const* d_in, const int* in_sizes, int n_in,
                              void* d_out, int out_size, void* d_ws,
                              size_t ws_size, hipStream_t stream) {
  const float* img     = (const float*)d_in[0];
  const float* txt     = (const float*)d_in[1];
  const float* scale_p = (const float*)d_in[2];
  const float* bias_p  = (const float*)d_in[3];
  float* out = (float*)d_out;

  hipMemsetAsync(d_out, 0, (size_t)out_size * sizeof(float), stream);

  const size_t elems = (size_t)NROWS * DDIM;
  const size_t need  = 2 * elems * sizeof(unsigned short);  // 16.8 MB

  if (ws_size >= need) {
    unsigned short* Abf = (unsigned short*)d_ws;
    unsigned short* Bbf = Abf + elems;
    const int cast_blocks = (int)(elems / (256 * 8));  // 2048
    cast_bf16_kernel<<<cast_blocks, 256, 0, stream>>>(img, Abf);
    cast_bf16_kernel<<<cast_blocks, 256, 0, stream>>>(txt, Bbf);
    siglip_strip<<<512, 256, 0, stream>>>(Abf, Bbf, scale_p, bias_p, out);
    return;
  }
  const int nblocks = (NROWS / 128) * (NROWS / 128);  // 16384
  siglip_fallback<<<nblocks, 256, 0, stream>>>(img, txt, scale_p, bias_p, out);
}